// Round 4
// baseline (2121.049 us; speedup 1.0000x reference)
//
#include <hip/hip_runtime.h>
#include <hip/hip_bf16.h>

typedef short bf16x8 __attribute__((ext_vector_type(8)));
typedef float f32x4 __attribute__((ext_vector_type(4)));

#define LOG2E 1.4426950408889634f

__device__ __forceinline__ float fexp(float x){ return __builtin_amdgcn_exp2f(x * LOG2E); }
__device__ __forceinline__ float frcp(float x){ return __builtin_amdgcn_rcpf(x); }
__device__ __forceinline__ float tanh_fast(float x){ float e = fexp(2.f*x); return 1.f - 2.f*frcp(e + 1.f); }
__device__ __forceinline__ float sigm_fast(float x){ return frcp(1.f + fexp(-x)); }
__device__ __forceinline__ float elu_fast(float x){ return x > 0.f ? x : fexp(x) - 1.f; }
__device__ __forceinline__ float dot4(float4 a, float4 b){
  return (a.x*b.x + a.y*b.y) + (a.z*b.z + a.w*b.w);
}
__device__ __forceinline__ float wsum(float v){
  #pragma unroll
  for (int o = 32; o > 0; o >>= 1) v += __shfl_xor(v, o, 64);
  return v;
}
__device__ __forceinline__ unsigned pk2(float a, float b){
  unsigned lo = __bfloat16_as_ushort(__float2bfloat16(a));
  unsigned hi = __bfloat16_as_ushort(__float2bfloat16(b));
  return lo | (hi << 16);
}
__device__ __forceinline__ float bflo(unsigned u){ return __uint_as_float(u << 16); }
__device__ __forceinline__ float bfhi(unsigned u){ return __uint_as_float(u & 0xffff0000u); }
__device__ __forceinline__ unsigned short bfq(float a){
  return __bfloat16_as_ushort(__float2bfloat16(a));
}

// A-fragment LDS tile: [kt][lanep][8 bf16] with XOR swizzle.
__device__ __forceinline__ int afrag_off(int kt, int lanep){
  int off = (kt << 10) + (lanep << 4);
  off ^= ((lanep >> 4) & 1) << 5;
  off ^= (kt & 1) << 6;
  return off;
}

// ---------------------------------------------------------------------------
// K0: pack B-operand MFMA fragments (bf16) for the 3 GEMMs + bio.
// ---------------------------------------------------------------------------
__global__ void k_prep(const float* __restrict__ FC1_w, const float* __restrict__ W_hh,
                       const float* __restrict__ FCout1_w,
                       const float* __restrict__ b_ih, const float* __restrict__ b_hh,
                       unsigned short* __restrict__ B1f, unsigned short* __restrict__ B2f,
                       unsigned short* __restrict__ B3f, float* __restrict__ bio)
{
  int n = blockIdx.x * 256 + threadIdx.x;
  if (n < 32768) {              // B1: Wds (K=256, N=128), NT=8 KT=8
    int jj = n & 7, lane = (n >> 3) & 63, ktn = n >> 9;
    int kt = ktn & 7, nt = ktn >> 3;
    int nn = nt*16 + (lane & 15), k = kt*32 + ((lane >> 4) << 3) + jj;
    B1f[n] = bfq(FC1_w[nn*384 + k]);
  } else if (n < 98304) {       // B2: Whh (K=128, N=512), NT=32 KT=4
    int n2 = n - 32768;
    int jj = n2 & 7, lane = (n2 >> 3) & 63, ktn = n2 >> 9;
    int kt = ktn & 3, nt = ktn >> 2;
    int nn = nt*16 + (lane & 15), k = kt*32 + ((lane >> 4) << 3) + jj;
    B2f[n2] = bfq(W_hh[nn*128 + k]);
  } else if (n < 131072) {      // B3: Fo1 (K=256, N=128), NT=8 KT=8
    int n3 = n - 98304;
    int jj = n3 & 7, lane = (n3 >> 3) & 63, ktn = n3 >> 9;
    int kt = ktn & 7, nt = ktn >> 3;
    int nn = nt*16 + (lane & 15), k = kt*32 + ((lane >> 4) << 3) + jj;
    B3f[n3] = bfq(FCout1_w[nn*256 + k]);
  } else if (n < 131584) {
    int n4 = n - 131072;
    bio[n4] = b_ih[n4] + b_hh[n4];
  }
}

// ---------------------------------------------------------------------------
// K1: HWp[b][m4][t]{4 bf16} = FC1_w[m][256+k].H[b][t][k] + FC1_b[m]; H->bf16.
// ---------------------------------------------------------------------------
__global__ __launch_bounds__(256) void k_hw(
    const float* __restrict__ H, const float* __restrict__ FC1_w,
    const float* __restrict__ FC1_b, unsigned short* __restrict__ HWp,
    unsigned short* __restrict__ Hbf)
{
  __shared__ __align__(16) float Hl[64][128];
  const int b = blockIdx.x, tid = threadIdx.x;
  const float* Hb = H + (size_t)b * 8192;
  for (int i = tid; i < 8192; i += 256) ((float*)Hl)[i] = Hb[i];
  __syncthreads();

  if (Hbf) {
    unsigned* Ho = (unsigned*)Hbf + (size_t)b * 4096;
    for (int i = tid; i < 4096; i += 256) {
      float2 v = ((const float2*)Hl)[i];
      Ho[i] = pk2(v.x, v.y);
    }
  }

  const int m = tid >> 1, t0 = (tid & 1) * 32;
  float acc[32];
  const float bias = FC1_b[m];
  #pragma unroll
  for (int j = 0; j < 32; ++j) acc[j] = bias;

  const float* wrow = FC1_w + m*384 + 256;
  for (int k4 = 0; k4 < 32; ++k4) {
    float4 w = *(const float4*)(wrow + 4*k4);
    #pragma unroll
    for (int j = 0; j < 32; ++j) {
      float4 h = *(const float4*)&Hl[t0 + j][4*k4];
      acc[j] += dot4(w, h);
    }
  }
  unsigned short* o = HWp + (((size_t)b*32 + (m >> 2))*64 + t0)*4 + (m & 3);
  #pragma unroll
  for (int j = 0; j < 32; ++j)
    o[j*4] = bfq(acc[j]);
}

// ---------------------------------------------------------------------------
// K2: recurrence. 256 blocks x 16 waves; block owns 8 rows; wave (r,h) owns
// output half oi = h*64+lane of row r. h=0 waves run a-GEMM, h=1 out-GEMM
// (deferred one step), all waves run a 32-col gate-GEMM slice. 4 barriers/step.
// ---------------------------------------------------------------------------
template<bool HB>
__global__ __launch_bounds__(1024, 4) void k_main(
    const float* __restrict__ H, const float* __restrict__ Y,
    const unsigned short* __restrict__ HWp, const unsigned short* __restrict__ Hbf,
    const unsigned short* __restrict__ B1f, const unsigned short* __restrict__ B2f,
    const unsigned short* __restrict__ B3f, const float* __restrict__ bio,
    const float* __restrict__ FC2_w, const float* __restrict__ FCin_w,
    const float* __restrict__ FCin_b, const float* __restrict__ W_ih,
    const float* __restrict__ FCout1_b, const float* __restrict__ FCout2_w,
    const float* __restrict__ FCout2_b, float* __restrict__ out, int L)
{
  __shared__ __align__(16) char  AFds[8192];      // A-frags [d|s] bf16 (K=256)
  __shared__ __align__(16) char  AFdc[8192];      // A-frags [d|C] bf16 (K=256)
  __shared__ __align__(16) float a_l[8][128];
  __shared__ __align__(16) float ho_l[8][128];
  __shared__ __align__(16) float gate_l[8][512];
  __shared__ __align__(16) float lgp[8][2][64];
  __shared__ float redp[8][2], outp[8][2];
  __shared__ __align__(16) float fc2s[128], fo2s[128], fo1bs[128], fcinC[128];
  __shared__ __align__(16) float bios[512], wihs[512];
  __shared__ float scal[4];

  const int tid = threadIdx.x, w = tid >> 6, lane = tid & 63;
  const int r = w >> 1, h = w & 1;
  const int oi = h*64 + lane;

  if (tid < 128) {
    fc2s[tid] = FC2_w[tid]; fo2s[tid] = FCout2_w[tid];
    fo1bs[tid] = FCout1_b[tid]; fcinC[tid] = FCin_w[1 + tid];
  }
  if (tid >= 256 && tid < 768) { bios[tid-256] = bio[tid-256]; wihs[tid-256] = W_ih[tid-256]; }
  if (tid == 0) { scal[0] = FCin_b[0]; scal[1] = FCout2_b[0]; scal[2] = FCin_w[0]; }
  ((int*)AFds)[tid*2] = 0; ((int*)AFds)[tid*2+1] = 0;
  ((int*)AFdc)[tid*2] = 0; ((int*)AFdc)[tid*2+1] = 0;
  __syncthreads();

  // persistent weight fragments
  const bf16x8* BUv = (const bf16x8*)(h ? B3f : B1f);
  const bf16x8* B2v = (const bf16x8*)B2f;
  bf16x8 wAO[8], wG[2][4];
  #pragma unroll
  for (int kt = 0; kt < 8; ++kt) wAO[kt] = BUv[(r*8 + kt)*64 + lane];
  #pragma unroll
  for (int t2 = 0; t2 < 2; ++t2)
    #pragma unroll
    for (int kt = 0; kt < 4; ++kt) wG[t2][kt] = B2v[((w*2 + t2)*4 + kt)*64 + lane];

  const int b = blockIdx.x * 8 + r;
  const uint2* HWu = (const uint2*)HWp + (size_t)b * 2048 + (size_t)h * 1024;
  const unsigned* Hbu = (const unsigned*)Hbf + (size_t)b * 4096;
  const float* Hf = H + (size_t)b * 8192;
  const int hbase = h*32 + (lane >> 1);
  const int shamt = (lane & 1) ? 0 : 16;

  const int drow = (lane >> 4) * 4;
  const bool dvalid = (lane < 32);
  const int ncb = lane & 15;
  // fragment publish coords for state index oi
  const int p_kt = oi >> 5, p_g = (oi >> 3) & 3, p_bo = (oi & 7) * 2;
  const int p_off = afrag_off(p_kt, r + 16*p_g) + p_bo;
  const int p_off_s = afrag_off(4 + p_kt, r + 16*p_g) + p_bo;   // k = 128+oi

  float sst = 0.f;

  for (int step = 0; step < L; ++step) {
    // ---------- GEMM phase: a(t)+gates(t) [h=0], out(t-1)+gates(t) [h=1] ----
    f32x4 accU = {0.f,0.f,0.f,0.f};
    f32x4 aG0 = {0.f,0.f,0.f,0.f}, aG1 = {0.f,0.f,0.f,0.f};
    if (h == 0) {
      bf16x8 af[8];
      #pragma unroll
      for (int kt = 0; kt < 8; ++kt) af[kt] = *(const bf16x8*)&AFds[afrag_off(kt, lane)];
      #pragma unroll
      for (int kt = 0; kt < 8; ++kt)
        accU = __builtin_amdgcn_mfma_f32_16x16x32_bf16(af[kt], wAO[kt], accU, 0, 0, 0);
      #pragma unroll
      for (int kt = 0; kt < 4; ++kt) {
        aG0 = __builtin_amdgcn_mfma_f32_16x16x32_bf16(af[kt], wG[0][kt], aG0, 0, 0, 0);
        aG1 = __builtin_amdgcn_mfma_f32_16x16x32_bf16(af[kt], wG[1][kt], aG1, 0, 0, 0);
      }
    } else {
      if (step > 0) {
        #pragma unroll
        for (int kt = 0; kt < 8; ++kt) {
          bf16x8 afc = *(const bf16x8*)&AFdc[afrag_off(kt, lane)];
          accU = __builtin_amdgcn_mfma_f32_16x16x32_bf16(afc, wAO[kt], accU, 0, 0, 0);
        }
      }
      #pragma unroll
      for (int kt = 0; kt < 4; ++kt) {
        bf16x8 af2 = *(const bf16x8*)&AFds[afrag_off(kt, lane)];
        aG0 = __builtin_amdgcn_mfma_f32_16x16x32_bf16(af2, wG[0][kt], aG0, 0, 0, 0);
        aG1 = __builtin_amdgcn_mfma_f32_16x16x32_bf16(af2, wG[1][kt], aG1, 0, 0, 0);
      }
    }
    if (dvalid) {
      if (h == 0) {
        #pragma unroll
        for (int r2 = 0; r2 < 4; ++r2) a_l[drow + r2][r*16 + ncb] = accU[r2];
      } else if (step > 0) {
        #pragma unroll
        for (int r2 = 0; r2 < 4; ++r2) ho_l[drow + r2][r*16 + ncb] = accU[r2];
      }
      #pragma unroll
      for (int r2 = 0; r2 < 4; ++r2) {
        gate_l[drow + r2][(w*2)*16 + ncb]     = aG0[r2];
        gate_l[drow + r2][(w*2 + 1)*16 + ncb] = aG1[r2];
      }
    }
    __syncthreads();   // S1

    // ---------- Phase D (step-1): elu + FCout2 partial ----------
    if (step > 0) {
      float e = elu_fast(ho_l[r][oi] + fo1bs[oi]);
      float op = wsum(fo2s[oi] * e);
      if (lane == 0) outp[r][h] = op;
    }

    // ---------- Phase B1: logit partials over this wave's m-half ----------
    float lg0 = 0.f, lg1 = 0.f, lg2 = 0.f, lg3 = 0.f;
    #pragma unroll 4
    for (int m4 = 0; m4 < 16; ++m4) {
      uint2 u = HWu[m4*64 + lane];
      float4 av = *(const float4*)&a_l[r][h*64 + m4*4];
      float4 fv = *(const float4*)&fc2s[h*64 + m4*4];
      lg0 += fv.x * tanh_fast(av.x + bflo(u.x));
      lg1 += fv.y * tanh_fast(av.y + bfhi(u.x));
      lg2 += fv.z * tanh_fast(av.z + bflo(u.y));
      lg3 += fv.w * tanh_fast(av.w + bfhi(u.y));
    }
    lgp[r][h][lane] = (lg0 + lg1) + (lg2 + lg3);
    __syncthreads();   // Sa

    // ---------- deferred out-store for step-1 ----------
    if (step > 0 && h == 0 && lane == 0)
      out[(size_t)b*L + step - 1] = outp[r][0] + outp[r][1] + scal[1];

    // ---------- Phase B2: softmax (redundant per wave), C, li partial ------
    float lgt = lgp[r][0][lane] + lgp[r][1][lane];
    float ex = fexp(lgt);                 // |lgt| <~ 11, safe
    float alpha = ex * frcp(wsum(ex));

    float c = 0.f;
    #pragma unroll 8
    for (int t = 0; t < 64; ++t) {
      float at = __shfl(alpha, t);
      if (HB) {
        unsigned u = Hbu[t*64 + hbase];
        c += at * __uint_as_float((u << shamt) & 0xffff0000u);
      } else {
        c += at * Hf[t*128 + oi];
      }
    }
    float part = wsum(fcinC[oi] * c);
    if (lane == 0) redp[r][h] = part;
    __syncthreads();   // Sb

    // ---------- Phase B3: li, gates, LSTM update, publish frags ----------
    float yt = Y[(size_t)b*64 + step];
    float li = redp[r][0] + redp[r][1] + scal[2]*yt + scal[0];

    float gi = gate_l[r][      oi] + li*wihs[      oi] + bios[      oi];
    float gf = gate_l[r][128 + oi] + li*wihs[128 + oi] + bios[128 + oi];
    float gg = gate_l[r][256 + oi] + li*wihs[256 + oi] + bios[256 + oi];
    float go = gate_l[r][384 + oi] + li*wihs[384 + oi] + bios[384 + oi];

    sst = sigm_fast(gf)*sst + sigm_fast(gi)*tanh_fast(gg);
    float dn = sigm_fast(go)*tanh_fast(sst);

    unsigned short dq = bfq(dn), sq = bfq(sst), cq = bfq(c);
    *(unsigned short*)&AFds[p_off]   = dq;
    *(unsigned short*)&AFdc[p_off]   = dq;
    *(unsigned short*)&AFds[p_off_s] = sq;
    *(unsigned short*)&AFdc[p_off_s] = cq;
    __syncthreads();   // Sc
  }

  // ---------- tail: out-GEMM(L-1) + phase D + store ----------
  if (h == 1) {
    f32x4 accO = {0.f,0.f,0.f,0.f};
    #pragma unroll
    for (int kt = 0; kt < 8; ++kt) {
      bf16x8 afc = *(const bf16x8*)&AFdc[afrag_off(kt, lane)];
      accO = __builtin_amdgcn_mfma_f32_16x16x32_bf16(afc, wAO[kt], accO, 0, 0, 0);
    }
    if (dvalid) {
      #pragma unroll
      for (int r2 = 0; r2 < 4; ++r2) ho_l[drow + r2][r*16 + ncb] = accO[r2];
    }
  }
  __syncthreads();
  {
    float e = elu_fast(ho_l[r][oi] + fo1bs[oi]);
    float op = wsum(fo2s[oi] * e);
    if (lane == 0) outp[r][h] = op;
  }
  __syncthreads();
  if (h == 0 && lane == 0)
    out[(size_t)b*L + L - 1] = outp[r][0] + outp[r][1] + scal[1];
}

extern "C" void kernel_launch(void* const* d_in, const int* in_sizes, int n_in,
                              void* d_out, int out_size, void* d_ws, size_t ws_size,
                              hipStream_t stream) {
  const float* H        = (const float*)d_in[0];
  const float* y        = (const float*)d_in[1];
  const float* FC1_w    = (const float*)d_in[2];
  const float* FC1_b    = (const float*)d_in[3];
  const float* FC2_w    = (const float*)d_in[4];
  // d_in[5] = FC2_b (softmax-invariant, unused)
  const float* FCin_w   = (const float*)d_in[6];
  const float* FCin_b   = (const float*)d_in[7];
  const float* W_ih     = (const float*)d_in[8];
  const float* W_hh     = (const float*)d_in[9];
  const float* b_ih     = (const float*)d_in[10];
  const float* b_hh     = (const float*)d_in[11];
  const float* FCout1_w = (const float*)d_in[12];
  const float* FCout1_b = (const float*)d_in[13];
  const float* FCout2_w = (const float*)d_in[14];
  const float* FCout2_b = (const float*)d_in[15];
  float* out = (float*)d_out;
  const int L = out_size / 2048;   // target_length (= 64)

  char* ws = (char*)d_ws;
  unsigned short* B1f = (unsigned short*)(ws + 0);
  unsigned short* B2f = (unsigned short*)(ws + 65536);
  unsigned short* B3f = (unsigned short*)(ws + 196608);
  float*          bio = (float*)(ws + 262144);
  unsigned short* HWp = (unsigned short*)(ws + 264192);
  unsigned short* Hbf = (unsigned short*)(ws + 264192 + 33554432);
  const bool hb = ws_size >= (size_t)(264192 + 2*33554432);

  k_prep<<<514, 256, 0, stream>>>(FC1_w, W_hh, FCout1_w, b_ih, b_hh,
                                  B1f, B2f, B3f, bio);
  k_hw<<<2048, 256, 0, stream>>>(H, FC1_w, FC1_b, HWp, hb ? Hbf : nullptr);
  if (hb)
    k_main<true><<<256, 1024, 0, stream>>>(H, y, HWp, Hbf, B1f, B2f, B3f, bio,
                                           FC2_w, FCin_w, FCin_b, W_ih,
                                           FCout1_b, FCout2_w, FCout2_b, out, L);
  else
    k_main<false><<<256, 1024, 0, stream>>>(H, y, HWp, Hbf, B1f, B2f, B3f, bio,
                                            FC2_w, FCin_w, FCin_b, W_ih,
                                            FCout1_b, FCout2_w, FCout2_b, out, L);
}

// Round 5
// 1422.135 us; speedup vs baseline: 1.4915x; 1.4915x over previous
//
#include <hip/hip_runtime.h>
#include <hip/hip_bf16.h>

typedef short bf16x8 __attribute__((ext_vector_type(8)));
typedef float f32x4 __attribute__((ext_vector_type(4)));

#define LOG2E 1.4426950408889634f

__device__ __forceinline__ float fexp(float x){ return __builtin_amdgcn_exp2f(x * LOG2E); }
__device__ __forceinline__ float frcp(float x){ return __builtin_amdgcn_rcpf(x); }
__device__ __forceinline__ float tanh_fast(float x){ float e = fexp(2.f*x); return 1.f - 2.f*frcp(e + 1.f); }
__device__ __forceinline__ float sigm_fast(float x){ return frcp(1.f + fexp(-x)); }
__device__ __forceinline__ float elu_fast(float x){ return x > 0.f ? x : fexp(x) - 1.f; }
__device__ __forceinline__ float dot4(float4 a, float4 b){
  return (a.x*b.x + a.y*b.y) + (a.z*b.z + a.w*b.w);
}
__device__ __forceinline__ float wsum(float v){
  #pragma unroll
  for (int o = 32; o > 0; o >>= 1) v += __shfl_xor(v, o, 64);
  return v;
}
__device__ __forceinline__ unsigned pk2(float a, float b){
  unsigned lo = __bfloat16_as_ushort(__float2bfloat16(a));
  unsigned hi = __bfloat16_as_ushort(__float2bfloat16(b));
  return lo | (hi << 16);
}
__device__ __forceinline__ float bflo(unsigned u){ return __uint_as_float(u << 16); }
__device__ __forceinline__ float bfhi(unsigned u){ return __uint_as_float(u & 0xffff0000u); }
__device__ __forceinline__ unsigned short bfq(float a){
  return __bfloat16_as_ushort(__float2bfloat16(a));
}

// A-fragment LDS tile: [kt][lanep][8 bf16] with XOR swizzle.
__device__ __forceinline__ int afrag_off(int kt, int lanep){
  int off = (kt << 10) + (lanep << 4);
  off ^= ((lanep >> 4) & 1) << 5;
  off ^= (kt & 1) << 6;
  return off;
}

// ---------------------------------------------------------------------------
// K0: pack B-operand MFMA fragments (bf16) for the 3 GEMMs + bio.
// ---------------------------------------------------------------------------
__global__ void k_prep(const float* __restrict__ FC1_w, const float* __restrict__ W_hh,
                       const float* __restrict__ FCout1_w,
                       const float* __restrict__ b_ih, const float* __restrict__ b_hh,
                       unsigned short* __restrict__ B1f, unsigned short* __restrict__ B2f,
                       unsigned short* __restrict__ B3f, float* __restrict__ bio)
{
  int n = blockIdx.x * 256 + threadIdx.x;
  if (n < 32768) {              // B1: Wds (K=256, N=128), NT=8 KT=8
    int jj = n & 7, lane = (n >> 3) & 63, ktn = n >> 9;
    int kt = ktn & 7, nt = ktn >> 3;
    int nn = nt*16 + (lane & 15), k = kt*32 + ((lane >> 4) << 3) + jj;
    B1f[n] = bfq(FC1_w[nn*384 + k]);
  } else if (n < 98304) {       // B2: Whh (K=128, N=512), NT=32 KT=4
    int n2 = n - 32768;
    int jj = n2 & 7, lane = (n2 >> 3) & 63, ktn = n2 >> 9;
    int kt = ktn & 3, nt = ktn >> 2;
    int nn = nt*16 + (lane & 15), k = kt*32 + ((lane >> 4) << 3) + jj;
    B2f[n2] = bfq(W_hh[nn*128 + k]);
  } else if (n < 131072) {      // B3: Fo1 (K=256, N=128), NT=8 KT=8
    int n3 = n - 98304;
    int jj = n3 & 7, lane = (n3 >> 3) & 63, ktn = n3 >> 9;
    int kt = ktn & 7, nt = ktn >> 3;
    int nn = nt*16 + (lane & 15), k = kt*32 + ((lane >> 4) << 3) + jj;
    B3f[n3] = bfq(FCout1_w[nn*256 + k]);
  } else if (n < 131584) {
    int n4 = n - 131072;
    bio[n4] = b_ih[n4] + b_hh[n4];
  }
}

// ---------------------------------------------------------------------------
// K1: HWp[b][m4][t]{4 bf16} = FC1_w[m][256+k].H[b][t][k] + FC1_b[m]; H->bf16.
// ---------------------------------------------------------------------------
__global__ __launch_bounds__(256) void k_hw(
    const float* __restrict__ H, const float* __restrict__ FC1_w,
    const float* __restrict__ FC1_b, unsigned short* __restrict__ HWp,
    unsigned short* __restrict__ Hbf)
{
  __shared__ __align__(16) float Hl[64][128];
  const int b = blockIdx.x, tid = threadIdx.x;
  const float* Hb = H + (size_t)b * 8192;
  for (int i = tid; i < 8192; i += 256) ((float*)Hl)[i] = Hb[i];
  __syncthreads();

  if (Hbf) {
    unsigned* Ho = (unsigned*)Hbf + (size_t)b * 4096;
    for (int i = tid; i < 4096; i += 256) {
      float2 v = ((const float2*)Hl)[i];
      Ho[i] = pk2(v.x, v.y);
    }
  }

  const int m = tid >> 1, t0 = (tid & 1) * 32;
  float acc[32];
  const float bias = FC1_b[m];
  #pragma unroll
  for (int j = 0; j < 32; ++j) acc[j] = bias;

  const float* wrow = FC1_w + m*384 + 256;
  for (int k4 = 0; k4 < 32; ++k4) {
    float4 w = *(const float4*)(wrow + 4*k4);
    #pragma unroll
    for (int j = 0; j < 32; ++j) {
      float4 h = *(const float4*)&Hl[t0 + j][4*k4];
      acc[j] += dot4(w, h);
    }
  }
  unsigned short* o = HWp + (((size_t)b*32 + (m >> 2))*64 + t0)*4 + (m & 3);
  #pragma unroll
  for (int j = 0; j < 32; ++j)
    o[j*4] = bfq(acc[j]);
}

// ---------------------------------------------------------------------------
// K2: recurrence. 256 blocks x 16 waves; 8 rows/block; wave (r,h) owns half
// oi = h*64+lane of row r. UNIFORM GEMM path: every wave runs one U-GEMM
// ntile (h=0: a-GEMM from AFds/B1; h=1: out-GEMM(prev) from AFdc/B3 -- same
// code, pointer-selected) + 2 gate ntiles (d-half of either tile is
// identical, so afU[0..3] feeds the gate MFMAs in both roles). 4 barriers.
// ---------------------------------------------------------------------------
template<bool HB>
__global__ __launch_bounds__(1024, 4) void k_main(
    const float* __restrict__ H, const float* __restrict__ Y,
    const unsigned short* __restrict__ HWp, const unsigned short* __restrict__ Hbf,
    const unsigned short* __restrict__ B1f, const unsigned short* __restrict__ B2f,
    const unsigned short* __restrict__ B3f, const float* __restrict__ bio,
    const float* __restrict__ FC2_w, const float* __restrict__ FCin_w,
    const float* __restrict__ FCin_b, const float* __restrict__ W_ih,
    const float* __restrict__ FCout1_b, const float* __restrict__ FCout2_w,
    const float* __restrict__ FCout2_b, float* __restrict__ out, int L)
{
  __shared__ __align__(16) char  AFds[8192];      // A-frags [d|s] bf16 (K=256)
  __shared__ __align__(16) char  AFdc[8192];      // A-frags [d|C] bf16 (K=256)
  __shared__ __align__(16) float a_l[8][128];
  __shared__ __align__(16) float ho_l[8][128];
  __shared__ __align__(16) float gate_l[8][512];
  __shared__ __align__(16) float lgp[8][2][64];
  __shared__ __align__(16) float alpha_l[16][64];
  __shared__ float redp[8][2], outp[8][2];
  __shared__ __align__(16) float fc2s[128], fo2s[128], fo1bs[128], fcinC[128];
  __shared__ __align__(16) float bios[512], wihs[512];
  __shared__ float scal[4];

  const int tid = threadIdx.x, w = tid >> 6, lane = tid & 63;
  const int r = w >> 1, h = w & 1;
  const int oi = h*64 + lane;

  if (tid < 128) {
    fc2s[tid] = FC2_w[tid]; fo2s[tid] = FCout2_w[tid];
    fo1bs[tid] = FCout1_b[tid]; fcinC[tid] = FCin_w[1 + tid];
  }
  if (tid >= 512) { bios[tid-512] = bio[tid-512]; wihs[tid-512] = W_ih[tid-512]; }
  if (tid == 0) { scal[0] = FCin_b[0]; scal[1] = FCout2_b[0]; scal[2] = FCin_w[0]; }
  ((int*)AFds)[tid*2] = 0; ((int*)AFds)[tid*2+1] = 0;
  ((int*)AFdc)[tid*2] = 0; ((int*)AFdc)[tid*2+1] = 0;
  __syncthreads();

  // persistent weight fragments: uniform shape for every wave
  const bf16x8* BUv = (const bf16x8*)(h ? B3f : B1f);
  const bf16x8* B2v = (const bf16x8*)B2f;
  bf16x8 wU[8], wG[2][4];
  #pragma unroll
  for (int kt = 0; kt < 8; ++kt) wU[kt] = BUv[(r*8 + kt)*64 + lane];
  #pragma unroll
  for (int j2 = 0; j2 < 2; ++j2)
    #pragma unroll
    for (int kt = 0; kt < 4; ++kt) wG[j2][kt] = B2v[((w*2 + j2)*4 + kt)*64 + lane];

  const int b = blockIdx.x * 8 + r;
  const uint2* HWu = (const uint2*)HWp + (size_t)b * 2048 + (size_t)h * 1024;
  const unsigned* Hbu = (const unsigned*)Hbf + (size_t)b * 4096;
  const float* Hf = H + (size_t)b * 8192;
  const int hbase = h*32 + (lane >> 1);
  const int shamt = (lane & 1) ? 0 : 16;

  const int drow = (lane >> 4) * 4;
  const bool dvalid = (lane < 32);
  const int ncb = lane & 15;
  const char* Pa = h ? AFdc : AFds;                 // U-GEMM A-source
  float* Ud = h ? &ho_l[0][0] : &a_l[0][0];         // U-GEMM dest
  // fragment publish coords for state index oi
  const int p_g = (oi >> 3) & 3, p_bo = (oi & 7) * 2;
  const int p_off   = afrag_off(oi >> 5,       r + 16*p_g) + p_bo;
  const int p_off_s = afrag_off(4 + (oi >> 5), r + 16*p_g) + p_bo;   // k=128+oi

  float sst = 0.f;

  for (int step = 0; step < L; ++step) {
    // ---------- unified GEMM phase ----------
    bf16x8 afU[8];
    #pragma unroll
    for (int kt = 0; kt < 8; ++kt) afU[kt] = *(const bf16x8*)&Pa[afrag_off(kt, lane)];
    f32x4 accU = {0.f,0.f,0.f,0.f};
    #pragma unroll
    for (int kt = 0; kt < 8; ++kt)
      accU = __builtin_amdgcn_mfma_f32_16x16x32_bf16(afU[kt], wU[kt], accU, 0, 0, 0);
    f32x4 aG0 = {0.f,0.f,0.f,0.f}, aG1 = {0.f,0.f,0.f,0.f};
    #pragma unroll
    for (int kt = 0; kt < 4; ++kt) {
      aG0 = __builtin_amdgcn_mfma_f32_16x16x32_bf16(afU[kt], wG[0][kt], aG0, 0, 0, 0);
      aG1 = __builtin_amdgcn_mfma_f32_16x16x32_bf16(afU[kt], wG[1][kt], aG1, 0, 0, 0);
    }
    if (dvalid) {
      #pragma unroll
      for (int r2 = 0; r2 < 4; ++r2) {
        Ud[(drow + r2)*128 + r*16 + ncb] = accU[r2];
        gate_l[drow + r2][(w*2)*16 + ncb]     = aG0[r2];
        gate_l[drow + r2][(w*2 + 1)*16 + ncb] = aG1[r2];
      }
    }
    __syncthreads();   // S1

    // ---------- Phase D (step-1): elu + FCout2 partial ----------
    if (step > 0) {
      float e = elu_fast(ho_l[r][oi] + fo1bs[oi]);
      float op = wsum(fo2s[oi] * e);
      if (lane == 0) outp[r][h] = op;
    }

    // ---------- Phase B1: logit partials over this wave's m-half ----------
    float lg0 = 0.f, lg1 = 0.f, lg2 = 0.f, lg3 = 0.f;
    #pragma unroll 4
    for (int m4 = 0; m4 < 16; ++m4) {
      uint2 u = HWu[m4*64 + lane];
      float4 av = *(const float4*)&a_l[r][h*64 + m4*4];
      float4 fv = *(const float4*)&fc2s[h*64 + m4*4];
      lg0 += fv.x * tanh_fast(av.x + bflo(u.x));
      lg1 += fv.y * tanh_fast(av.y + bfhi(u.x));
      lg2 += fv.z * tanh_fast(av.z + bflo(u.y));
      lg3 += fv.w * tanh_fast(av.w + bfhi(u.y));
    }
    lgp[r][h][lane] = (lg0 + lg1) + (lg2 + lg3);
    __syncthreads();   // Sa

    // ---------- deferred out-store for step-1 ----------
    if (step > 0 && h == 0 && lane == 0)
      out[(size_t)b*L + step - 1] = outp[r][0] + outp[r][1] + scal[1];

    // ---------- Phase B2: softmax (per-wave), C half, li partial ----------
    float lgt = lgp[r][0][lane] + lgp[r][1][lane];
    float ex = fexp(lgt);                 // |lgt| <~ 11, safe without max-sub
    float alpha = ex * frcp(wsum(ex));
    alpha_l[w][lane] = alpha;

    float c = 0.f;
    #pragma unroll 4
    for (int t4 = 0; t4 < 16; ++t4) {
      float4 av = *(const float4*)&alpha_l[w][t4*4];
      if (HB) {
        unsigned u0 = Hbu[(t4*4 + 0)*64 + hbase];
        unsigned u1 = Hbu[(t4*4 + 1)*64 + hbase];
        unsigned u2 = Hbu[(t4*4 + 2)*64 + hbase];
        unsigned u3 = Hbu[(t4*4 + 3)*64 + hbase];
        c += av.x * __uint_as_float((u0 << shamt) & 0xffff0000u);
        c += av.y * __uint_as_float((u1 << shamt) & 0xffff0000u);
        c += av.z * __uint_as_float((u2 << shamt) & 0xffff0000u);
        c += av.w * __uint_as_float((u3 << shamt) & 0xffff0000u);
      } else {
        c += av.x * Hf[(t4*4 + 0)*128 + oi];
        c += av.y * Hf[(t4*4 + 1)*128 + oi];
        c += av.z * Hf[(t4*4 + 2)*128 + oi];
        c += av.w * Hf[(t4*4 + 3)*128 + oi];
      }
    }
    float part = wsum(fcinC[oi] * c);
    if (lane == 0) redp[r][h] = part;
    __syncthreads();   // Sb

    // ---------- Phase B3: li, gates, LSTM update, publish frags ----------
    float yt = Y[(size_t)b*64 + step];
    float li = redp[r][0] + redp[r][1] + scal[2]*yt + scal[0];

    float gi = gate_l[r][      oi] + li*wihs[      oi] + bios[      oi];
    float gf = gate_l[r][128 + oi] + li*wihs[128 + oi] + bios[128 + oi];
    float gg = gate_l[r][256 + oi] + li*wihs[256 + oi] + bios[256 + oi];
    float go = gate_l[r][384 + oi] + li*wihs[384 + oi] + bios[384 + oi];

    sst = sigm_fast(gf)*sst + sigm_fast(gi)*tanh_fast(gg);
    float dn = sigm_fast(go)*tanh_fast(sst);

    unsigned short dq = bfq(dn), sq = bfq(sst), cq = bfq(c);
    *(unsigned short*)&AFds[p_off]   = dq;
    *(unsigned short*)&AFdc[p_off]   = dq;
    *(unsigned short*)&AFds[p_off_s] = sq;
    *(unsigned short*)&AFdc[p_off_s] = cq;
    __syncthreads();   // Sc
  }

  // ---------- tail: out-GEMM(L-1) + phase D + store ----------
  if (h == 1) {
    bf16x8 afc[8];
    #pragma unroll
    for (int kt = 0; kt < 8; ++kt) afc[kt] = *(const bf16x8*)&AFdc[afrag_off(kt, lane)];
    f32x4 accO = {0.f,0.f,0.f,0.f};
    #pragma unroll
    for (int kt = 0; kt < 8; ++kt)
      accO = __builtin_amdgcn_mfma_f32_16x16x32_bf16(afc[kt], wU[kt], accO, 0, 0, 0);
    if (dvalid) {
      #pragma unroll
      for (int r2 = 0; r2 < 4; ++r2) ho_l[drow + r2][r*16 + ncb] = accO[r2];
    }
  }
  __syncthreads();
  {
    float e = elu_fast(ho_l[r][oi] + fo1bs[oi]);
    float op = wsum(fo2s[oi] * e);
    if (lane == 0) outp[r][h] = op;
  }
  __syncthreads();
  if (h == 0 && lane == 0)
    out[(size_t)b*L + L - 1] = outp[r][0] + outp[r][1] + scal[1];
}

extern "C" void kernel_launch(void* const* d_in, const int* in_sizes, int n_in,
                              void* d_out, int out_size, void* d_ws, size_t ws_size,
                              hipStream_t stream) {
  const float* H        = (const float*)d_in[0];
  const float* y        = (const float*)d_in[1];
  const float* FC1_w    = (const float*)d_in[2];
  const float* FC1_b    = (const float*)d_in[3];
  const float* FC2_w    = (const float*)d_in[4];
  // d_in[5] = FC2_b (softmax-invariant, unused)
  const float* FCin_w   = (const float*)d_in[6];
  const float* FCin_b   = (const float*)d_in[7];
  const float* W_ih     = (const float*)d_in[8];
  const float* W_hh     = (const float*)d_in[9];
  const float* b_ih     = (const float*)d_in[10];
  const float* b_hh     = (const float*)d_in[11];
  const float* FCout1_w = (const float*)d_in[12];
  const float* FCout1_b = (const float*)d_in[13];
  const float* FCout2_w = (const float*)d_in[14];
  const float* FCout2_b = (const float*)d_in[15];
  float* out = (float*)d_out;
  const int L = out_size / 2048;   // target_length (= 64)

  char* ws = (char*)d_ws;
  unsigned short* B1f = (unsigned short*)(ws + 0);
  unsigned short* B2f = (unsigned short*)(ws + 65536);
  unsigned short* B3f = (unsigned short*)(ws + 196608);
  float*          bio = (float*)(ws + 262144);
  unsigned short* HWp = (unsigned short*)(ws + 264192);
  unsigned short* Hbf = (unsigned short*)(ws + 264192 + 33554432);
  const bool hb = ws_size >= (size_t)(264192 + 2*33554432);

  k_prep<<<514, 256, 0, stream>>>(FC1_w, W_hh, FCout1_w, b_ih, b_hh,
                                  B1f, B2f, B3f, bio);
  k_hw<<<2048, 256, 0, stream>>>(H, FC1_w, FC1_b, HWp, hb ? Hbf : nullptr);
  if (hb)
    k_main<true><<<256, 1024, 0, stream>>>(H, y, HWp, Hbf, B1f, B2f, B3f, bio,
                                           FC2_w, FCin_w, FCin_b, W_ih,
                                           FCout1_b, FCout2_w, FCout2_b, out, L);
  else
    k_main<false><<<256, 1024, 0, stream>>>(H, y, HWp, Hbf, B1f, B2f, B3f, bio,
                                            FC2_w, FCin_w, FCin_b, W_ih,
                                            FCout1_b, FCout2_w, FCout2_b, out, L);
}

// Round 6
// 1320.479 us; speedup vs baseline: 1.6063x; 1.0770x over previous
//
#include <hip/hip_runtime.h>
#include <hip/hip_bf16.h>

typedef short bf16x8 __attribute__((ext_vector_type(8)));
typedef float f32x4 __attribute__((ext_vector_type(4)));

#define LOG2E 1.4426950408889634f

__device__ __forceinline__ float fexp(float x){ return __builtin_amdgcn_exp2f(x * LOG2E); }
__device__ __forceinline__ float frcp(float x){ return __builtin_amdgcn_rcpf(x); }
__device__ __forceinline__ float tanh_fast(float x){ float e = fexp(2.f*x); return 1.f - 2.f*frcp(e + 1.f); }
__device__ __forceinline__ float sigm_fast(float x){ return frcp(1.f + fexp(-x)); }
__device__ __forceinline__ float elu_fast(float x){ return x > 0.f ? x : fexp(x) - 1.f; }
__device__ __forceinline__ float dot4(float4 a, float4 b){
  return (a.x*b.x + a.y*b.y) + (a.z*b.z + a.w*b.w);
}
__device__ __forceinline__ float wsum(float v){
  #pragma unroll
  for (int o = 32; o > 0; o >>= 1) v += __shfl_xor(v, o, 64);
  return v;
}
__device__ __forceinline__ unsigned pk2(float a, float b){
  unsigned lo = __bfloat16_as_ushort(__float2bfloat16(a));
  unsigned hi = __bfloat16_as_ushort(__float2bfloat16(b));
  return lo | (hi << 16);
}
__device__ __forceinline__ float bflo(unsigned u){ return __uint_as_float(u << 16); }
__device__ __forceinline__ float bfhi(unsigned u){ return __uint_as_float(u & 0xffff0000u); }
__device__ __forceinline__ unsigned short bfq(float a){
  return __bfloat16_as_ushort(__float2bfloat16(a));
}

// A-fragment LDS tile: [kt][lanep][8 bf16] with XOR swizzle.
__device__ __forceinline__ int afrag_off(int kt, int lanep){
  int off = (kt << 10) + (lanep << 4);
  off ^= ((lanep >> 4) & 1) << 5;
  off ^= (kt & 1) << 6;
  return off;
}

// ---------------------------------------------------------------------------
// K0: pack B-operand MFMA fragments (bf16) for the 3 GEMMs + bio.
// ---------------------------------------------------------------------------
__global__ void k_prep(const float* __restrict__ FC1_w, const float* __restrict__ W_hh,
                       const float* __restrict__ FCout1_w,
                       const float* __restrict__ b_ih, const float* __restrict__ b_hh,
                       unsigned short* __restrict__ B1f, unsigned short* __restrict__ B2f,
                       unsigned short* __restrict__ B3f, float* __restrict__ bio)
{
  int n = blockIdx.x * 256 + threadIdx.x;
  if (n < 32768) {              // B1: Wds (K=256, N=128), NT=8 KT=8
    int jj = n & 7, lane = (n >> 3) & 63, ktn = n >> 9;
    int kt = ktn & 7, nt = ktn >> 3;
    int nn = nt*16 + (lane & 15), k = kt*32 + ((lane >> 4) << 3) + jj;
    B1f[n] = bfq(FC1_w[nn*384 + k]);
  } else if (n < 98304) {       // B2: Whh (K=128, N=512), NT=32 KT=4
    int n2 = n - 32768;
    int jj = n2 & 7, lane = (n2 >> 3) & 63, ktn = n2 >> 9;
    int kt = ktn & 3, nt = ktn >> 2;
    int nn = nt*16 + (lane & 15), k = kt*32 + ((lane >> 4) << 3) + jj;
    B2f[n2] = bfq(W_hh[nn*128 + k]);
  } else if (n < 131072) {      // B3: Fo1 (K=256, N=128), NT=8 KT=8
    int n3 = n - 98304;
    int jj = n3 & 7, lane = (n3 >> 3) & 63, ktn = n3 >> 9;
    int kt = ktn & 7, nt = ktn >> 3;
    int nn = nt*16 + (lane & 15), k = kt*32 + ((lane >> 4) << 3) + jj;
    B3f[n3] = bfq(FCout1_w[nn*256 + k]);
  } else if (n < 131584) {
    int n4 = n - 131072;
    bio[n4] = b_ih[n4] + b_hh[n4];
  }
}

// ---------------------------------------------------------------------------
// K1: HWp[b][m4][t]{4 bf16} = FC1_w[m][256+k].H[b][t][k] + FC1_b[m]; H->bf16.
// ---------------------------------------------------------------------------
__global__ __launch_bounds__(256) void k_hw(
    const float* __restrict__ H, const float* __restrict__ FC1_w,
    const float* __restrict__ FC1_b, unsigned short* __restrict__ HWp,
    unsigned short* __restrict__ Hbf)
{
  __shared__ __align__(16) float Hl[64][128];
  const int b = blockIdx.x, tid = threadIdx.x;
  const float* Hb = H + (size_t)b * 8192;
  for (int i = tid; i < 8192; i += 256) ((float*)Hl)[i] = Hb[i];
  __syncthreads();

  if (Hbf) {
    unsigned* Ho = (unsigned*)Hbf + (size_t)b * 4096;
    for (int i = tid; i < 4096; i += 256) {
      float2 v = ((const float2*)Hl)[i];
      Ho[i] = pk2(v.x, v.y);
    }
  }

  const int m = tid >> 1, t0 = (tid & 1) * 32;
  float acc[32];
  const float bias = FC1_b[m];
  #pragma unroll
  for (int j = 0; j < 32; ++j) acc[j] = bias;

  const float* wrow = FC1_w + m*384 + 256;
  for (int k4 = 0; k4 < 32; ++k4) {
    float4 w = *(const float4*)(wrow + 4*k4);
    #pragma unroll
    for (int j = 0; j < 32; ++j) {
      float4 h = *(const float4*)&Hl[t0 + j][4*k4];
      acc[j] += dot4(w, h);
    }
  }
  unsigned short* o = HWp + (((size_t)b*32 + (m >> 2))*64 + t0)*4 + (m & 3);
  #pragma unroll
  for (int j = 0; j < 32; ++j)
    o[j*4] = bfq(acc[j]);
}

// ---------------------------------------------------------------------------
// K2: recurrence. 256 blocks x 16 waves; 8 rows/block; wave (r,h) owns half
// oi = h*64+lane of row r. Uniform GEMM path (h=0: a-GEMM; h=1: deferred
// out-GEMM), gate MFMAs fused into the first 4 kt (shared d-half).
// A-fragments loaded incrementally (8 dw live, not 32) to avoid spills.
// ---------------------------------------------------------------------------
template<bool HB>
__global__ __launch_bounds__(1024, 4) void k_main(
    const float* __restrict__ H, const float* __restrict__ Y,
    const unsigned short* __restrict__ HWp, const unsigned short* __restrict__ Hbf,
    const unsigned short* __restrict__ B1f, const unsigned short* __restrict__ B2f,
    const unsigned short* __restrict__ B3f, const float* __restrict__ bio,
    const float* __restrict__ FC2_w, const float* __restrict__ FCin_w,
    const float* __restrict__ FCin_b, const float* __restrict__ W_ih,
    const float* __restrict__ FCout1_b, const float* __restrict__ FCout2_w,
    const float* __restrict__ FCout2_b, float* __restrict__ out, int L)
{
  __shared__ __align__(16) char  AFds[8192];      // A-frags [d|s] bf16 (K=256)
  __shared__ __align__(16) char  AFdc[8192];      // A-frags [d|C] bf16 (K=256)
  __shared__ __align__(16) float a_l[8][128];
  __shared__ __align__(16) float ho_l[8][128];
  __shared__ __align__(16) float gate_l[8][512];
  __shared__ __align__(16) float lgp[8][2][64];
  __shared__ __align__(16) float alpha_l[16][64];
  __shared__ float redp[8][2], outp[8][2];
  __shared__ __align__(16) float fc2s[128], fo2s[128], fo1bs[128], fcinC[128];
  __shared__ __align__(16) float bios[512], wihs[512];
  __shared__ float scal[4];

  const int tid = threadIdx.x, w = tid >> 6, lane = tid & 63;
  const int r = w >> 1, h = w & 1;
  const int oi = h*64 + lane;

  if (tid < 128) {
    fc2s[tid] = FC2_w[tid]; fo2s[tid] = FCout2_w[tid];
    fo1bs[tid] = FCout1_b[tid]; fcinC[tid] = FCin_w[1 + tid];
  }
  if (tid >= 512) { bios[tid-512] = bio[tid-512]; wihs[tid-512] = W_ih[tid-512]; }
  if (tid == 0) { scal[0] = FCin_b[0]; scal[1] = FCout2_b[0]; scal[2] = FCin_w[0]; }
  ((int*)AFds)[tid*2] = 0; ((int*)AFds)[tid*2+1] = 0;
  ((int*)AFdc)[tid*2] = 0; ((int*)AFdc)[tid*2+1] = 0;
  __syncthreads();

  // persistent weight fragments: uniform shape for every wave
  const bf16x8* BUv = (const bf16x8*)(h ? B3f : B1f);
  const bf16x8* B2v = (const bf16x8*)B2f;
  bf16x8 wU[8], wG[2][4];
  #pragma unroll
  for (int kt = 0; kt < 8; ++kt) wU[kt] = BUv[(r*8 + kt)*64 + lane];
  #pragma unroll
  for (int j2 = 0; j2 < 2; ++j2)
    #pragma unroll
    for (int kt = 0; kt < 4; ++kt) wG[j2][kt] = B2v[((w*2 + j2)*4 + kt)*64 + lane];

  const int b = blockIdx.x * 8 + r;
  const uint2* HWu = (const uint2*)HWp + (size_t)b * 2048 + (size_t)h * 1024;
  const unsigned* Hbu = (const unsigned*)Hbf + (size_t)b * 4096;
  const float* Hf = H + (size_t)b * 8192;
  const int hbase = h*32 + (lane >> 1);
  const int shamt = (lane & 1) ? 0 : 16;

  const int drow = (lane >> 4) * 4;
  const bool dvalid = (lane < 32);
  const int ncb = lane & 15;
  const char* Pa = h ? AFdc : AFds;                 // U-GEMM A-source
  float* Ud = h ? &ho_l[0][0] : &a_l[0][0];         // U-GEMM dest
  // fragment publish coords for state index oi
  const int p_g = (oi >> 3) & 3, p_bo = (oi & 7) * 2;
  const int p_off   = afrag_off(oi >> 5,       r + 16*p_g) + p_bo;
  const int p_off_s = afrag_off(4 + (oi >> 5), r + 16*p_g) + p_bo;   // k=128+oi

  float sst = 0.f;

  for (int step = 0; step < L; ++step) {
    // ---------- unified GEMM phase (incremental A-fragment load) ----------
    f32x4 accU = {0.f,0.f,0.f,0.f};
    f32x4 aG0 = {0.f,0.f,0.f,0.f}, aG1 = {0.f,0.f,0.f,0.f};
    #pragma unroll
    for (int kt = 0; kt < 4; ++kt) {
      bf16x8 a = *(const bf16x8*)&Pa[afrag_off(kt, lane)];   // d-half (shared)
      accU = __builtin_amdgcn_mfma_f32_16x16x32_bf16(a, wU[kt], accU, 0, 0, 0);
      aG0  = __builtin_amdgcn_mfma_f32_16x16x32_bf16(a, wG[0][kt], aG0, 0, 0, 0);
      aG1  = __builtin_amdgcn_mfma_f32_16x16x32_bf16(a, wG[1][kt], aG1, 0, 0, 0);
    }
    #pragma unroll
    for (int kt = 4; kt < 8; ++kt) {
      bf16x8 a = *(const bf16x8*)&Pa[afrag_off(kt, lane)];   // s/C-half
      accU = __builtin_amdgcn_mfma_f32_16x16x32_bf16(a, wU[kt], accU, 0, 0, 0);
    }
    if (dvalid) {
      #pragma unroll
      for (int r2 = 0; r2 < 4; ++r2) {
        Ud[(drow + r2)*128 + r*16 + ncb] = accU[r2];
        gate_l[drow + r2][(w*2)*16 + ncb]     = aG0[r2];
        gate_l[drow + r2][(w*2 + 1)*16 + ncb] = aG1[r2];
      }
    }
    __syncthreads();   // S1

    // ---------- Phase D (step-1): elu + FCout2 partial ----------
    if (step > 0) {
      float e = elu_fast(ho_l[r][oi] + fo1bs[oi]);
      float op = wsum(fo2s[oi] * e);
      if (lane == 0) outp[r][h] = op;
    }

    // ---------- Phase B1: logit partials over this wave's m-half ----------
    float lg0 = 0.f, lg1 = 0.f;
    #pragma unroll 2
    for (int m4 = 0; m4 < 16; ++m4) {
      uint2 u = HWu[m4*64 + lane];
      float4 av = *(const float4*)&a_l[r][h*64 + m4*4];
      float4 fv = *(const float4*)&fc2s[h*64 + m4*4];
      lg0 += fv.x * tanh_fast(av.x + bflo(u.x));
      lg1 += fv.y * tanh_fast(av.y + bfhi(u.x));
      lg0 += fv.z * tanh_fast(av.z + bflo(u.y));
      lg1 += fv.w * tanh_fast(av.w + bfhi(u.y));
    }
    lgp[r][h][lane] = lg0 + lg1;
    __syncthreads();   // Sa

    // ---------- deferred out-store for step-1 ----------
    if (step > 0 && h == 0 && lane == 0)
      out[(size_t)b*L + step - 1] = outp[r][0] + outp[r][1] + scal[1];

    // ---------- Phase B2: softmax (per-wave), C half, li partial ----------
    float lgt = lgp[r][0][lane] + lgp[r][1][lane];
    float ex = fexp(lgt);                 // |lgt| <~ 11, safe without max-sub
    float alpha = ex * frcp(wsum(ex));
    alpha_l[w][lane] = alpha;

    float c = 0.f;
    #pragma unroll 4
    for (int t4 = 0; t4 < 16; ++t4) {
      float4 av = *(const float4*)&alpha_l[w][t4*4];
      if (HB) {
        unsigned u0 = Hbu[(t4*4 + 0)*64 + hbase];
        unsigned u1 = Hbu[(t4*4 + 1)*64 + hbase];
        unsigned u2 = Hbu[(t4*4 + 2)*64 + hbase];
        unsigned u3 = Hbu[(t4*4 + 3)*64 + hbase];
        c += av.x * __uint_as_float((u0 << shamt) & 0xffff0000u);
        c += av.y * __uint_as_float((u1 << shamt) & 0xffff0000u);
        c += av.z * __uint_as_float((u2 << shamt) & 0xffff0000u);
        c += av.w * __uint_as_float((u3 << shamt) & 0xffff0000u);
      } else {
        c += av.x * Hf[(t4*4 + 0)*128 + oi];
        c += av.y * Hf[(t4*4 + 1)*128 + oi];
        c += av.z * Hf[(t4*4 + 2)*128 + oi];
        c += av.w * Hf[(t4*4 + 3)*128 + oi];
      }
    }
    float part = wsum(fcinC[oi] * c);
    if (lane == 0) redp[r][h] = part;
    __syncthreads();   // Sb

    // ---------- Phase B3: li, gates, LSTM update, publish frags ----------
    float yt = Y[(size_t)b*64 + step];
    float li = redp[r][0] + redp[r][1] + scal[2]*yt + scal[0];

    float gi = gate_l[r][      oi] + li*wihs[      oi] + bios[      oi];
    float gf = gate_l[r][128 + oi] + li*wihs[128 + oi] + bios[128 + oi];
    float gg = gate_l[r][256 + oi] + li*wihs[256 + oi] + bios[256 + oi];
    float go = gate_l[r][384 + oi] + li*wihs[384 + oi] + bios[384 + oi];

    sst = sigm_fast(gf)*sst + sigm_fast(gi)*tanh_fast(gg);
    float dn = sigm_fast(go)*tanh_fast(sst);

    unsigned short dq = bfq(dn), sq = bfq(sst), cq = bfq(c);
    *(unsigned short*)&AFds[p_off]   = dq;
    *(unsigned short*)&AFdc[p_off]   = dq;
    *(unsigned short*)&AFds[p_off_s] = sq;
    *(unsigned short*)&AFdc[p_off_s] = cq;
    __syncthreads();   // Sc
  }

  // ---------- tail: out-GEMM(L-1) + phase D + store ----------
  if (h == 1) {
    f32x4 accO = {0.f,0.f,0.f,0.f};
    #pragma unroll
    for (int kt = 0; kt < 8; ++kt) {
      bf16x8 a = *(const bf16x8*)&AFdc[afrag_off(kt, lane)];
      accO = __builtin_amdgcn_mfma_f32_16x16x32_bf16(a, wU[kt], accO, 0, 0, 0);
    }
    if (dvalid) {
      #pragma unroll
      for (int r2 = 0; r2 < 4; ++r2) ho_l[drow + r2][r*16 + ncb] = accO[r2];
    }
  }
  __syncthreads();
  {
    float e = elu_fast(ho_l[r][oi] + fo1bs[oi]);
    float op = wsum(fo2s[oi] * e);
    if (lane == 0) outp[r][h] = op;
  }
  __syncthreads();
  if (h == 0 && lane == 0)
    out[(size_t)b*L + L - 1] = outp[r][0] + outp[r][1] + scal[1];
}

extern "C" void kernel_launch(void* const* d_in, const int* in_sizes, int n_in,
                              void* d_out, int out_size, void* d_ws, size_t ws_size,
                              hipStream_t stream) {
  const float* H        = (const float*)d_in[0];
  const float* y        = (const float*)d_in[1];
  const float* FC1_w    = (const float*)d_in[2];
  const float* FC1_b    = (const float*)d_in[3];
  const float* FC2_w    = (const float*)d_in[4];
  // d_in[5] = FC2_b (softmax-invariant, unused)
  const float* FCin_w   = (const float*)d_in[6];
  const float* FCin_b   = (const float*)d_in[7];
  const float* W_ih     = (const float*)d_in[8];
  const float* W_hh     = (const float*)d_in[9];
  const float* b_ih     = (const float*)d_in[10];
  const float* b_hh     = (const float*)d_in[11];
  const float* FCout1_w = (const float*)d_in[12];
  const float* FCout1_b = (const float*)d_in[13];
  const float* FCout2_w = (const float*)d_in[14];
  const float* FCout2_b = (const float*)d_in[15];
  float* out = (float*)d_out;
  const int L = out_size / 2048;   // target_length (= 64)

  char* ws = (char*)d_ws;
  unsigned short* B1f = (unsigned short*)(ws + 0);
  unsigned short* B2f = (unsigned short*)(ws + 65536);
  unsigned short* B3f = (unsigned short*)(ws + 196608);
  float*          bio = (float*)(ws + 262144);
  unsigned short* HWp = (unsigned short*)(ws + 264192);
  unsigned short* Hbf = (unsigned short*)(ws + 264192 + 33554432);
  const bool hb = ws_size >= (size_t)(264192 + 2*33554432);

  k_prep<<<514, 256, 0, stream>>>(FC1_w, W_hh, FCout1_w, b_ih, b_hh,
                                  B1f, B2f, B3f, bio);
  k_hw<<<2048, 256, 0, stream>>>(H, FC1_w, FC1_b, HWp, hb ? Hbf : nullptr);
  if (hb)
    k_main<true><<<256, 1024, 0, stream>>>(H, y, HWp, Hbf, B1f, B2f, B3f, bio,
                                           FC2_w, FCin_w, FCin_b, W_ih,
                                           FCout1_b, FCout2_w, FCout2_b, out, L);
  else
    k_main<false><<<256, 1024, 0, stream>>>(H, y, HWp, Hbf, B1f, B2f, B3f, bio,
                                            FC2_w, FCin_w, FCin_b, W_ih,
                                            FCout1_b, FCout2_w, FCout2_b, out, L);
}

// Round 8
// 1223.376 us; speedup vs baseline: 1.7338x; 1.0794x over previous
//
#include <hip/hip_runtime.h>
#include <hip/hip_bf16.h>

typedef short bf16x8 __attribute__((ext_vector_type(8)));
typedef float f32x4 __attribute__((ext_vector_type(4)));

#define LOG2E 1.4426950408889634f

__device__ __forceinline__ float fexp(float x){ return __builtin_amdgcn_exp2f(x * LOG2E); }
__device__ __forceinline__ float frcp(float x){ return __builtin_amdgcn_rcpf(x); }
__device__ __forceinline__ float tanh_fast(float x){ float e = fexp(2.f*x); return 1.f - 2.f*frcp(e + 1.f); }
__device__ __forceinline__ float sigm_fast(float x){ return frcp(1.f + fexp(-x)); }
__device__ __forceinline__ float elu_fast(float x){ return x > 0.f ? x : fexp(x) - 1.f; }
__device__ __forceinline__ float dot4(float4 a, float4 b){
  return (a.x*b.x + a.y*b.y) + (a.z*b.z + a.w*b.w);
}
__device__ __forceinline__ float wsum(float v){
  #pragma unroll
  for (int o = 32; o > 0; o >>= 1) v += __shfl_xor(v, o, 64);
  return v;
}
__device__ __forceinline__ unsigned pk2(float a, float b){
  unsigned lo = __bfloat16_as_ushort(__float2bfloat16(a));
  unsigned hi = __bfloat16_as_ushort(__float2bfloat16(b));
  return lo | (hi << 16);
}
__device__ __forceinline__ float bflo(unsigned u){ return __uint_as_float(u << 16); }
__device__ __forceinline__ float bfhi(unsigned u){ return __uint_as_float(u & 0xffff0000u); }
__device__ __forceinline__ unsigned short bfq(float a){
  return __bfloat16_as_ushort(__float2bfloat16(a));
}

// A-fragment LDS tile: [kt][lanep][8 bf16] with XOR swizzle.
__device__ __forceinline__ int afrag_off(int kt, int lanep){
  int off = (kt << 10) + (lanep << 4);
  off ^= ((lanep >> 4) & 1) << 5;
  off ^= (kt & 1) << 6;
  return off;
}

// ---------------------------------------------------------------------------
// K0: pack B-operand MFMA fragments (bf16) for the 3 GEMMs + bio.
// ---------------------------------------------------------------------------
__global__ void k_prep(const float* __restrict__ FC1_w, const float* __restrict__ W_hh,
                       const float* __restrict__ FCout1_w,
                       const float* __restrict__ b_ih, const float* __restrict__ b_hh,
                       unsigned short* __restrict__ B1f, unsigned short* __restrict__ B2f,
                       unsigned short* __restrict__ B3f, float* __restrict__ bio)
{
  int n = blockIdx.x * 256 + threadIdx.x;
  if (n < 32768) {              // B1: Wds (K=256, N=128), NT=8 KT=8
    int jj = n & 7, lane = (n >> 3) & 63, ktn = n >> 9;
    int kt = ktn & 7, nt = ktn >> 3;
    int nn = nt*16 + (lane & 15), k = kt*32 + ((lane >> 4) << 3) + jj;
    B1f[n] = bfq(FC1_w[nn*384 + k]);
  } else if (n < 98304) {       // B2: Whh (K=128, N=512), NT=32 KT=4
    int n2 = n - 32768;
    int jj = n2 & 7, lane = (n2 >> 3) & 63, ktn = n2 >> 9;
    int kt = ktn & 3, nt = ktn >> 2;
    int nn = nt*16 + (lane & 15), k = kt*32 + ((lane >> 4) << 3) + jj;
    B2f[n2] = bfq(W_hh[nn*128 + k]);
  } else if (n < 131072) {      // B3: Fo1 (K=256, N=128), NT=8 KT=8
    int n3 = n - 98304;
    int jj = n3 & 7, lane = (n3 >> 3) & 63, ktn = n3 >> 9;
    int kt = ktn & 7, nt = ktn >> 3;
    int nn = nt*16 + (lane & 15), k = kt*32 + ((lane >> 4) << 3) + jj;
    B3f[n3] = bfq(FCout1_w[nn*256 + k]);
  } else if (n < 131584) {
    int n4 = n - 131072;
    bio[n4] = b_ih[n4] + b_hh[n4];
  }
}

// ---------------------------------------------------------------------------
// K1: HWp[b][m4][t]{4 bf16} = FC1_w[m][256+k].H[b][t][k] + FC1_b[m];
//     P[b][t] = sum_k H[b][t][k] * FCin_w[1+k];  H->bf16 (Hbf).
// ---------------------------------------------------------------------------
__global__ __launch_bounds__(256) void k_hw(
    const float* __restrict__ H, const float* __restrict__ FC1_w,
    const float* __restrict__ FC1_b, const float* __restrict__ FCin_w,
    unsigned short* __restrict__ HWp, float* __restrict__ P,
    unsigned short* __restrict__ Hbf)
{
  __shared__ __align__(16) float Hl[64][128];
  const int b = blockIdx.x, tid = threadIdx.x;
  const float* Hb = H + (size_t)b * 8192;
  for (int i = tid; i < 8192; i += 256) ((float*)Hl)[i] = Hb[i];
  __syncthreads();

  if (Hbf) {
    unsigned* Ho = (unsigned*)Hbf + (size_t)b * 4096;
    for (int i = tid; i < 4096; i += 256) {
      float2 v = ((const float2*)Hl)[i];
      Ho[i] = pk2(v.x, v.y);
    }
  }
  if (tid < 64) {   // P[b][t]
    float acc = 0.f;
    #pragma unroll 8
    for (int k4 = 0; k4 < 32; ++k4) {
      float4 h = *(const float4*)&Hl[tid][4*k4];
      float4 f = *(const float4*)&FCin_w[1 + 4*k4];
      acc += dot4(h, f);
    }
    P[(size_t)b*64 + tid] = acc;
  }

  const int m = tid >> 1, t0 = (tid & 1) * 32;
  float acc[32];
  const float bias = FC1_b[m];
  #pragma unroll
  for (int j = 0; j < 32; ++j) acc[j] = bias;

  const float* wrow = FC1_w + m*384 + 256;
  for (int k4 = 0; k4 < 32; ++k4) {
    float4 w = *(const float4*)(wrow + 4*k4);
    #pragma unroll
    for (int j = 0; j < 32; ++j) {
      float4 h = *(const float4*)&Hl[t0 + j][4*k4];
      acc[j] += dot4(w, h);
    }
  }
  unsigned short* o = HWp + (((size_t)b*32 + (m >> 2))*64 + t0)*4 + (m & 3);
  #pragma unroll
  for (int j = 0; j < 32; ++j)
    o[j*4] = bfq(acc[j]);
}

// ---------------------------------------------------------------------------
// K2: recurrence. 256 blocks x 16 waves; 8 rows/block; wave (r,h) owns half
// oi = h*64+lane of row r. Persistent regs: wU (32 dw) only; gate weights
// streamed from L2 each step. li via precomputed P (no cross-half barrier).
// 3 barriers/step.
// ---------------------------------------------------------------------------
template<bool HB>
__global__ __launch_bounds__(1024, 4) void k_main(
    const float* __restrict__ Hf_, const float* __restrict__ Y,
    const unsigned short* __restrict__ HWp, const unsigned short* __restrict__ Hbf,
    const unsigned short* __restrict__ B1f, const unsigned short* __restrict__ B2f,
    const unsigned short* __restrict__ B3f, const float* __restrict__ bio,
    const float* __restrict__ FC2_w, const float* __restrict__ Pg,
    const float* __restrict__ FCin_w, const float* __restrict__ FCin_b,
    const float* __restrict__ W_ih,
    const float* __restrict__ FCout1_b, const float* __restrict__ FCout2_w,
    const float* __restrict__ FCout2_b, float* __restrict__ out, int L)
{
  __shared__ __align__(16) char  AFds[8192];      // A-frags [d|s] bf16 (K=256)
  __shared__ __align__(16) char  AFdc[8192];      // A-frags [d|C] bf16 (K=256)
  __shared__ __align__(16) float a_l[8][128];
  __shared__ __align__(16) float ho_l[8][128];
  __shared__ __align__(16) float gate_l[8][512];
  __shared__ __align__(16) float lgp[8][2][64];
  __shared__ __align__(16) float alpha_l[16][64];
  __shared__ __align__(16) float y_l[8][64];
  __shared__ float outp[8][2];
  __shared__ __align__(16) float fc2s[128], fo2s[128], fo1bs[128];
  __shared__ __align__(16) float bios[512], wihs[512];
  __shared__ float scal[4];

  const int tid = threadIdx.x, w = tid >> 6, lane = tid & 63;
  const int r = w >> 1, h = w & 1;
  const int oi = h*64 + lane;

  if (tid < 128) {
    fc2s[tid] = FC2_w[tid]; fo2s[tid] = FCout2_w[tid];
    fo1bs[tid] = FCout1_b[tid];
  }
  if (tid >= 512) { bios[tid-512] = bio[tid-512]; wihs[tid-512] = W_ih[tid-512]; }
  if (tid >= 128 && tid < 640) {
    int t2 = tid - 128;
    y_l[t2 >> 6][t2 & 63] = Y[((size_t)(blockIdx.x*8 + (t2 >> 6)))*64 + (t2 & 63)];
  }
  if (tid == 0) { scal[0] = FCin_b[0]; scal[1] = FCout2_b[0]; scal[2] = FCin_w[0]; }
  ((int*)AFds)[tid*2] = 0; ((int*)AFds)[tid*2+1] = 0;
  ((int*)AFdc)[tid*2] = 0; ((int*)AFdc)[tid*2+1] = 0;
  __syncthreads();

  // persistent: wU only (h=0: B1 ntile r; h=1: B3 ntile r)
  const bf16x8* BUv = (const bf16x8*)(h ? B3f : B1f);
  const bf16x8* B2v = (const bf16x8*)B2f;
  bf16x8 wU[8];
  #pragma unroll
  for (int kt = 0; kt < 8; ++kt) wU[kt] = BUv[(r*8 + kt)*64 + lane];
  const int b2base = w*512 + lane;     // + kt*64 (+256 for second ntile)

  const int b = blockIdx.x * 8 + r;
  const uint2* HWu = (const uint2*)HWp + (size_t)b * 2048 + (size_t)h * 1024;
  const unsigned* Hbu = (const unsigned*)Hbf + (size_t)b * 4096;
  const float* Hf = Hf_ + (size_t)b * 8192;
  const float pP = Pg[(size_t)b*64 + lane];     // P[b][t=lane], step-invariant
  const int hbase = h*32 + (lane >> 1);
  const int shamt = (lane & 1) ? 0 : 16;        // even lane -> low half (u<<16)

  const int drow = (lane >> 4) * 4;
  const bool dvalid = (lane < 32);
  const int ncb = lane & 15;
  const char* Pa = h ? AFdc : AFds;                 // U-GEMM A-source
  float* Ud = h ? &ho_l[0][0] : &a_l[0][0];         // U-GEMM dest
  // fragment publish coords for state index oi
  const int p_g = (oi >> 3) & 3, p_bo = (oi & 7) * 2;
  const int p_off   = afrag_off(oi >> 5,       r + 16*p_g) + p_bo;
  const int p_off_s = afrag_off(4 + (oi >> 5), r + 16*p_g) + p_bo;   // k=128+oi

  float sst = 0.f;

  for (int step = 0; step < L; ++step) {
    // ---------- GEMM phase ----------
    // stream gate-weight fragments from L2 (issued first, consumed last)
    bf16x8 g00 = B2v[b2base      ], g01 = B2v[b2base +  64];
    bf16x8 g02 = B2v[b2base + 128], g03 = B2v[b2base + 192];
    bf16x8 g10 = B2v[b2base + 256], g11 = B2v[b2base + 320];
    bf16x8 g12 = B2v[b2base + 384], g13 = B2v[b2base + 448];

    bf16x8 afd0 = *(const bf16x8*)&Pa[afrag_off(0, lane)];
    bf16x8 afd1 = *(const bf16x8*)&Pa[afrag_off(1, lane)];
    bf16x8 afd2 = *(const bf16x8*)&Pa[afrag_off(2, lane)];
    bf16x8 afd3 = *(const bf16x8*)&Pa[afrag_off(3, lane)];
    f32x4 accU = {0.f,0.f,0.f,0.f};
    accU = __builtin_amdgcn_mfma_f32_16x16x32_bf16(afd0, wU[0], accU, 0, 0, 0);
    accU = __builtin_amdgcn_mfma_f32_16x16x32_bf16(afd1, wU[1], accU, 0, 0, 0);
    accU = __builtin_amdgcn_mfma_f32_16x16x32_bf16(afd2, wU[2], accU, 0, 0, 0);
    accU = __builtin_amdgcn_mfma_f32_16x16x32_bf16(afd3, wU[3], accU, 0, 0, 0);
    #pragma unroll
    for (int kt = 4; kt < 8; ++kt) {
      bf16x8 a = *(const bf16x8*)&Pa[afrag_off(kt, lane)];
      accU = __builtin_amdgcn_mfma_f32_16x16x32_bf16(a, wU[kt], accU, 0, 0, 0);
    }
    f32x4 aG0 = {0.f,0.f,0.f,0.f}, aG1 = {0.f,0.f,0.f,0.f};
    aG0 = __builtin_amdgcn_mfma_f32_16x16x32_bf16(afd0, g00, aG0, 0, 0, 0);
    aG1 = __builtin_amdgcn_mfma_f32_16x16x32_bf16(afd0, g10, aG1, 0, 0, 0);
    aG0 = __builtin_amdgcn_mfma_f32_16x16x32_bf16(afd1, g01, aG0, 0, 0, 0);
    aG1 = __builtin_amdgcn_mfma_f32_16x16x32_bf16(afd1, g11, aG1, 0, 0, 0);
    aG0 = __builtin_amdgcn_mfma_f32_16x16x32_bf16(afd2, g02, aG0, 0, 0, 0);
    aG1 = __builtin_amdgcn_mfma_f32_16x16x32_bf16(afd2, g12, aG1, 0, 0, 0);
    aG0 = __builtin_amdgcn_mfma_f32_16x16x32_bf16(afd3, g03, aG0, 0, 0, 0);
    aG1 = __builtin_amdgcn_mfma_f32_16x16x32_bf16(afd3, g13, aG1, 0, 0, 0);

    if (dvalid) {
      #pragma unroll
      for (int r2 = 0; r2 < 4; ++r2) {
        Ud[(drow + r2)*128 + r*16 + ncb] = accU[r2];
        gate_l[drow + r2][(w*2)*16 + ncb]     = aG0[r2];
        gate_l[drow + r2][(w*2 + 1)*16 + ncb] = aG1[r2];
      }
    }
    __syncthreads();   // S1

    // ---------- Phase D (step-1): elu + FCout2 partial ----------
    if (step > 0) {
      float e = elu_fast(ho_l[r][oi] + fo1bs[oi]);
      float op = wsum(fo2s[oi] * e);
      if (lane == 0) outp[r][h] = op;
    }

    // ---------- Phase B1: logit partials over this wave's m-half ----------
    float lg0 = 0.f, lg1 = 0.f;
    #pragma unroll 2
    for (int m4 = 0; m4 < 16; ++m4) {
      uint2 u = HWu[m4*64 + lane];
      float4 av = *(const float4*)&a_l[r][h*64 + m4*4];
      float4 fv = *(const float4*)&fc2s[h*64 + m4*4];
      lg0 += fv.x * tanh_fast(av.x + bflo(u.x));
      lg1 += fv.y * tanh_fast(av.y + bfhi(u.x));
      lg0 += fv.z * tanh_fast(av.z + bflo(u.y));
      lg1 += fv.w * tanh_fast(av.w + bfhi(u.y));
    }
    lgp[r][h][lane] = lg0 + lg1;
    __syncthreads();   // Sa

    // ---------- deferred out-store for step-1 ----------
    if (step > 0 && h == 0 && lane == 0)
      out[(size_t)b*L + step - 1] = outp[r][0] + outp[r][1] + scal[1];

    // ---------- Phase B2: softmax (per-wave), li, gates, LSTM ----------
    float lgt = lgp[r][0][lane] + lgp[r][1][lane];
    float ex = fexp(lgt);                 // |lgt| <~ 11, safe without max-sub
    float alpha = ex * frcp(wsum(ex));
    alpha_l[w][lane] = alpha;

    float yt = y_l[r][step];
    float li = wsum(alpha * pP) + scal[2]*yt + scal[0];

    float gi = gate_l[r][      oi] + li*wihs[      oi] + bios[      oi];
    float gf = gate_l[r][128 + oi] + li*wihs[128 + oi] + bios[128 + oi];
    float gg = gate_l[r][256 + oi] + li*wihs[256 + oi] + bios[256 + oi];
    float go = gate_l[r][384 + oi] + li*wihs[384 + oi] + bios[384 + oi];

    sst = sigm_fast(gf)*sst + sigm_fast(gi)*tanh_fast(gg);
    float dn = sigm_fast(go)*tanh_fast(sst);

    *(unsigned short*)&AFds[p_off]   = bfq(dn);
    *(unsigned short*)&AFdc[p_off]   = bfq(dn);
    *(unsigned short*)&AFds[p_off_s] = bfq(sst);

    // ---------- C half (needed only for out-GEMM operand) ----------
    float c = 0.f;
    #pragma unroll 4
    for (int t4 = 0; t4 < 16; ++t4) {
      float4 av = *(const float4*)&alpha_l[w][t4*4];
      if (HB) {
        unsigned u0 = Hbu[(t4*4 + 0)*64 + hbase];
        unsigned u1 = Hbu[(t4*4 + 1)*64 + hbase];
        unsigned u2 = Hbu[(t4*4 + 2)*64 + hbase];
        unsigned u3 = Hbu[(t4*4 + 3)*64 + hbase];
        c += av.x * __uint_as_float((u0 << shamt) & 0xffff0000u);
        c += av.y * __uint_as_float((u1 << shamt) & 0xffff0000u);
        c += av.z * __uint_as_float((u2 << shamt) & 0xffff0000u);
        c += av.w * __uint_as_float((u3 << shamt) & 0xffff0000u);
      } else {
        c += av.x * Hf[(t4*4 + 0)*128 + oi];
        c += av.y * Hf[(t4*4 + 1)*128 + oi];
        c += av.z * Hf[(t4*4 + 2)*128 + oi];
        c += av.w * Hf[(t4*4 + 3)*128 + oi];
      }
    }
    *(unsigned short*)&AFdc[p_off_s] = bfq(c);
    __syncthreads();   // Sc
  }

  // ---------- tail: out-GEMM(L-1) + phase D + store ----------
  if (h == 1) {
    f32x4 accO = {0.f,0.f,0.f,0.f};
    #pragma unroll
    for (int kt = 0; kt < 8; ++kt) {
      bf16x8 a = *(const bf16x8*)&AFdc[afrag_off(kt, lane)];
      accO = __builtin_amdgcn_mfma_f32_16x16x32_bf16(a, wU[kt], accO, 0, 0, 0);
    }
    if (dvalid) {
      #pragma unroll
      for (int r2 = 0; r2 < 4; ++r2) ho_l[drow + r2][r*16 + ncb] = accO[r2];
    }
  }
  __syncthreads();
  {
    float e = elu_fast(ho_l[r][oi] + fo1bs[oi]);
    float op = wsum(fo2s[oi] * e);
    if (lane == 0) outp[r][h] = op;
  }
  __syncthreads();
  if (h == 0 && lane == 0)
    out[(size_t)b*L + L - 1] = outp[r][0] + outp[r][1] + scal[1];
}

extern "C" void kernel_launch(void* const* d_in, const int* in_sizes, int n_in,
                              void* d_out, int out_size, void* d_ws, size_t ws_size,
                              hipStream_t stream) {
  const float* H        = (const float*)d_in[0];
  const float* y        = (const float*)d_in[1];
  const float* FC1_w    = (const float*)d_in[2];
  const float* FC1_b    = (const float*)d_in[3];
  const float* FC2_w    = (const float*)d_in[4];
  // d_in[5] = FC2_b (softmax-invariant, unused)
  const float* FCin_w   = (const float*)d_in[6];
  const float* FCin_b   = (const float*)d_in[7];
  const float* W_ih     = (const float*)d_in[8];
  const float* W_hh     = (const float*)d_in[9];
  const float* b_ih     = (const float*)d_in[10];
  const float* b_hh     = (const float*)d_in[11];
  const float* FCout1_w = (const float*)d_in[12];
  const float* FCout1_b = (const float*)d_in[13];
  const float* FCout2_w = (const float*)d_in[14];
  const float* FCout2_b = (const float*)d_in[15];
  float* out = (float*)d_out;
  const int L = out_size / 2048;   // target_length (= 64)

  char* ws = (char*)d_ws;
  unsigned short* B1f = (unsigned short*)(ws + 0);        //  64 KB
  unsigned short* B2f = (unsigned short*)(ws + 65536);    // 128 KB
  unsigned short* B3f = (unsigned short*)(ws + 196608);   //  64 KB
  float*          bio = (float*)(ws + 262144);            //   2 KB
  float*          P   = (float*)(ws + 264192);            // 512 KB
  unsigned short* HWp = (unsigned short*)(ws + 788480);   //  32 MB
  unsigned short* Hbf = (unsigned short*)(ws + 788480 + 33554432);  // 32 MB
  const bool hb = ws_size >= (size_t)(788480 + 2*33554432);

  k_prep<<<514, 256, 0, stream>>>(FC1_w, W_hh, FCout1_w, b_ih, b_hh,
                                  B1f, B2f, B3f, bio);
  k_hw<<<2048, 256, 0, stream>>>(H, FC1_w, FC1_b, FCin_w, HWp, P,
                                 hb ? Hbf : nullptr);
  if (hb)
    k_main<true><<<256, 1024, 0, stream>>>(H, y, HWp, Hbf, B1f, B2f, B3f, bio,
                                           FC2_w, P, FCin_w, FCin_b, W_ih,
                                           FCout1_b, FCout2_w, FCout2_b, out, L);
  else
    k_main<false><<<256, 1024, 0, stream>>>(H, y, HWp, Hbf, B1f, B2f, B3f, bio,
                                            FC2_w, P, FCin_w, FCin_b, W_ih,
                                            FCout1_b, FCout2_w, FCout2_b, out, L);
}